// Round 1
// baseline (5928.811 us; speedup 1.0000x reference)
//
#include <hip/hip_runtime.h>
#include <float.h>

#define M_TOT 16384          // B*S tokens
#define H_DIM 2048
#define NV    5000
#define NVP1  5001
#define POOL_ROW_STRIDE (33 * 2048)
#define POOL_LAYER_OFF  (16 * 2048)   // LAYER_IDX = 16

#define MT 128               // rows per block
#define NT 256               // cols per chunk
#define KT 32                // K chunk
#define NSPLIT 4             // N split across blockIdx.y
#define NCHUNK 5             // chunks per split: 4*5*256 = 5120 >= 5001
#define COLS_PER_SPLIT (NCHUNK * NT)

// ---------------------------------------------------------------------------
// Kernel A: tiled fp32 GEMM (x @ gate_w^T + gate_b) fused with running argmax.
// Each block: 128 tokens x 1280 gate columns. Thread micro-tile: 8 rows x 16 cols.
// LDS tiles stored transposed [K][M], [K][N] -> fragment reads are float4 with
// broadcast across lanes (conflict-free / 2-way).
// ---------------------------------------------------------------------------
__global__ __launch_bounds__(256, 2)
void gemm_argmax_kernel(const float* __restrict__ x,
                        const float* __restrict__ gw,
                        const float* __restrict__ gb,
                        float* __restrict__ pval,
                        int*   __restrict__ pidx)
{
    __shared__ float xl[KT * MT];   // [k][m]  32*128 = 16 KB
    __shared__ float wl[KT * NT];   // [k][n]  32*256 = 32 KB
    __shared__ float bl[NT];

    const int t  = threadIdx.x;
    const int tx = t & 15;          // column group 0..15
    const int ty = t >> 4;          // row group    0..15
    const int m0 = blockIdx.x * MT;
    const int split = blockIdx.y;

    float bestv[8];
    int   besti[8];
#pragma unroll
    for (int i = 0; i < 8; ++i) { bestv[i] = -FLT_MAX; besti[i] = 0x7fffffff; }

    for (int nc = 0; nc < NCHUNK; ++nc) {
        const int n0 = split * COLS_PER_SPLIT + nc * NT;

        __syncthreads();                       // protect bl vs previous chunk's argmax
        bl[t] = (n0 + t < NVP1) ? gb[n0 + t] : 0.0f;

        float acc[8][16];
#pragma unroll
        for (int i = 0; i < 8; ++i)
#pragma unroll
            for (int j = 0; j < 16; ++j) acc[i][j] = 0.0f;

        for (int kc = 0; kc < H_DIM / KT; ++kc) {
            const int k0 = kc * KT;
            __syncthreads();                   // tiles consumed, safe to overwrite
            // stage x tile: 4 float4 per thread, transposed into [k][m]
#pragma unroll
            for (int p = 0; p < 4; ++p) {
                const int f   = t + 256 * p;   // 0..1023
                const int row = f >> 3;        // 0..127
                const int k4  = (f & 7) << 2;  // 0,4,...,28
                const float4 v = *(const float4*)(x + (size_t)(m0 + row) * H_DIM + k0 + k4);
                xl[(k4 + 0) * MT + row] = v.x;
                xl[(k4 + 1) * MT + row] = v.y;
                xl[(k4 + 2) * MT + row] = v.z;
                xl[(k4 + 3) * MT + row] = v.w;
            }
            // stage w tile: 8 float4 per thread, transposed into [k][n]
#pragma unroll
            for (int p = 0; p < 8; ++p) {
                const int f   = t + 256 * p;   // 0..2047
                const int row = f >> 3;        // 0..255
                const int k4  = (f & 7) << 2;
                const int n   = n0 + row;
                float4 v = make_float4(0.f, 0.f, 0.f, 0.f);
                if (n < NVP1) v = *(const float4*)(gw + (size_t)n * H_DIM + k0 + k4);
                wl[(k4 + 0) * NT + row] = v.x;
                wl[(k4 + 1) * NT + row] = v.y;
                wl[(k4 + 2) * NT + row] = v.z;
                wl[(k4 + 3) * NT + row] = v.w;
            }
            __syncthreads();
            // inner K loop: 128 FMAs per thread per k-step
#pragma unroll
            for (int kk = 0; kk < KT; ++kk) {
                const float4 A0 = *(const float4*)&xl[kk * MT + ty * 8];
                const float4 A1 = *(const float4*)&xl[kk * MT + ty * 8 + 4];
                const float a[8] = {A0.x, A0.y, A0.z, A0.w, A1.x, A1.y, A1.z, A1.w};
#pragma unroll
                for (int q = 0; q < 4; ++q) {
                    const float4 B = *(const float4*)&wl[kk * NT + q * 64 + tx * 4];
                    const float b4[4] = {B.x, B.y, B.z, B.w};
#pragma unroll
                    for (int i = 0; i < 8; ++i)
#pragma unroll
                        for (int j = 0; j < 4; ++j)
                            acc[i][q * 4 + j] = fmaf(a[i], b4[j], acc[i][q * 4 + j]);
                }
            }
        }

        // argmax over this N-chunk (add bias, mask padded cols, tie -> lowest idx)
#pragma unroll
        for (int i = 0; i < 8; ++i) {
            float bv = -FLT_MAX;
            int   bi = 0x7fffffff;
#pragma unroll
            for (int q = 0; q < 4; ++q)
#pragma unroll
                for (int j = 0; j < 4; ++j) {
                    const int nl = q * 64 + tx * 4 + j;
                    const int n  = n0 + nl;
                    float v = acc[i][q * 4 + j] + bl[nl];
                    if (n >= NVP1) v = -FLT_MAX;
                    if (v > bv || (v == bv && n < bi)) { bv = v; bi = n; }
                }
            // reduce across the 16 lanes sharing these rows
#pragma unroll
            for (int m = 1; m < 16; m <<= 1) {
                const float ov = __shfl_xor(bv, m, 64);
                const int   oi = __shfl_xor(bi, m, 64);
                if (ov > bv || (ov == bv && oi < bi)) { bv = ov; bi = oi; }
            }
            if (bv > bestv[i] || (bv == bestv[i] && bi < besti[i])) { bestv[i] = bv; besti[i] = bi; }
        }
    }

    if (tx == 0) {
#pragma unroll
        for (int i = 0; i < 8; ++i) {
            const int row = m0 + ty * 8 + i;
            pval[split * M_TOT + row] = bestv[i];
            pidx[split * M_TOT + row] = besti[i];
        }
    }
}

// ---------------------------------------------------------------------------
// Kernel B: merge the 4 split-partials per token, then gather the output row.
// ---------------------------------------------------------------------------
__global__ __launch_bounds__(256)
void merge_gather_kernel(const float* __restrict__ x,
                         const float* __restrict__ pool,
                         const float* __restrict__ pval,
                         const int*   __restrict__ pidx,
                         float* __restrict__ out)
{
    const int token = blockIdx.x;
    float bv = -FLT_MAX;
    int   bi = 0x7fffffff;
#pragma unroll
    for (int s = 0; s < NSPLIT; ++s) {
        const float v = pval[s * M_TOT + token];
        const int   i = pidx[s * M_TOT + token];
        if (v > bv || (v == bv && i < bi)) { bv = v; bi = i; }
    }
    const float4* src;
    if (bi == NV) {
        src = (const float4*)(x + (size_t)token * H_DIM);           // identity slot
    } else {
        const int safe = (bi < NV) ? bi : (NV - 1);
        src = (const float4*)(pool + (size_t)safe * POOL_ROW_STRIDE + POOL_LAYER_OFF);
    }
    float4* dst = (float4*)(out + (size_t)token * H_DIM);
    const int t = threadIdx.x;
    dst[t]       = src[t];
    dst[t + 256] = src[t + 256];
}

extern "C" void kernel_launch(void* const* d_in, const int* in_sizes, int n_in,
                              void* d_out, int out_size, void* d_ws, size_t ws_size,
                              hipStream_t stream)
{
    const float* x    = (const float*)d_in[0];
    const float* gw   = (const float*)d_in[1];
    const float* gb   = (const float*)d_in[2];
    const float* pool = (const float*)d_in[3];
    float* out  = (float*)d_out;

    float* pval = (float*)d_ws;
    int*   pidx = (int*)((char*)d_ws + (size_t)NSPLIT * M_TOT * sizeof(float));

    dim3 gridA(M_TOT / MT, NSPLIT);
    gemm_argmax_kernel<<<gridA, 256, 0, stream>>>(x, gw, gb, pval, pidx);
    merge_gather_kernel<<<M_TOT, 256, 0, stream>>>(x, pool, pval, pidx, out);
}

// Round 2
// 610.195 us; speedup vs baseline: 9.7163x; 9.7163x over previous
//
#include <hip/hip_runtime.h>
#include <float.h>

#define M_TOT 16384
#define H_DIM 2048
#define NV    5000
#define NVP1  5001
#define N_PAD 5120
#define POOL_ROW_STRIDE (33 * 2048)
#define POOL_LAYER_OFF  (16 * 2048)

#define BM 128
#define BN 128
#define BK 64
#define NTILES (N_PAD / BN)        // 40
#define NCHUNK (NTILES * 2)        // 80 column-chunks of 64
#define MARGIN 0.03f
#define MAXJOBS M_TOT

typedef __attribute__((ext_vector_type(8))) short short8;
typedef __attribute__((ext_vector_type(4))) float f32x4;

__device__ __forceinline__ void load16_to_lds(const void* g, void* l) {
    __builtin_amdgcn_global_load_lds((const __attribute__((address_space(1))) void*)g,
                                     (__attribute__((address_space(3))) void*)l, 16, 0, 0);
}

__device__ __forceinline__ unsigned short f2bf(float f) {
    unsigned u = __float_as_uint(f);
    return (unsigned short)((u + 0x7FFFu + ((u >> 16) & 1u)) >> 16);
}

// ---------------------------------------------------------------------------
// fp32 -> bf16 converts
// ---------------------------------------------------------------------------
__global__ __launch_bounds__(256) void conv_x_kernel(const float* __restrict__ x,
                                                     unsigned short* __restrict__ xbf) {
    const int stride = gridDim.x * blockDim.x;
    for (int i = blockIdx.x * blockDim.x + threadIdx.x; i < (M_TOT * H_DIM / 4); i += stride) {
        float4 v = ((const float4*)x)[i];
        ushort4 o = make_ushort4(f2bf(v.x), f2bf(v.y), f2bf(v.z), f2bf(v.w));
        ((ushort4*)xbf)[i] = o;
    }
}

__global__ __launch_bounds__(256) void conv_w_kernel(const float* __restrict__ gw,
                                                     unsigned short* __restrict__ wbf) {
    const int stride = gridDim.x * blockDim.x;
    for (int i = blockIdx.x * blockDim.x + threadIdx.x; i < (N_PAD * H_DIM / 4); i += stride) {
        const int row = i >> 9;               // 512 float4 per row
        ushort4 o = make_ushort4(0, 0, 0, 0);
        if (row < NVP1) {
            float4 v = ((const float4*)gw)[i];
            o = make_ushort4(f2bf(v.x), f2bf(v.y), f2bf(v.z), f2bf(v.w));
        }
        ((ushort4*)wbf)[i] = o;
    }
}

// ---------------------------------------------------------------------------
// MFMA bf16 GEMM (x_bf @ gw_bf^T) fused with per-64-col-chunk top-2 tracking.
// 128x128 tile, BK=64, 4 waves (2x2), each wave 64x64 via 4x4 16x16x32 frags.
// LDS XOR-swizzle (slot ^= row&7) applied via pre-swizzled global source so
// global_load_lds dest stays linear; ds_read applies the same swizzle.
// ---------------------------------------------------------------------------
__global__ __launch_bounds__(256, 2)
void gemm_top2_kernel(const unsigned short* __restrict__ xbf,
                      const unsigned short* __restrict__ wbf,
                      const float* __restrict__ gb,
                      float* __restrict__ pv1, int* __restrict__ pi1,
                      float* __restrict__ pv2, int* __restrict__ pi2)
{
    __shared__ __align__(16) char albuf[BM * BK * 2];   // 16 KB, row stride 128B
    __shared__ __align__(16) char blbuf[BN * BK * 2];   // 16 KB
    __shared__ float bl[BN];

    const int t    = threadIdx.x;
    const int w    = t >> 6;
    const int lane = t & 63;
    const int wm   = w >> 1;
    const int wn   = w & 1;
    const int bid  = blockIdx.x;
    const int nt   = bid % NTILES;
    const int mt   = bid / NTILES;
    const int m0   = mt * BM;
    const int n0   = nt * BN;

    if (t < BN) bl[t] = (n0 + t < NVP1) ? gb[n0 + t] : 0.0f;

    // per-wave staging pointers: wave w covers rows w*32 .. w*32+31 (4 insts x 8 rows)
    const int srow  = lane >> 3;
    const int sslot = lane & 7;
    const char* agp[4];
    const char* bgp[4];
#pragma unroll
    for (int p = 0; p < 4; ++p) {
        const int r = w * 32 + p * 8 + srow;
        agp[p] = (const char*)xbf + (size_t)(m0 + r) * (H_DIM * 2) + ((sslot ^ (r & 7)) << 4);
        bgp[p] = (const char*)wbf + (size_t)(n0 + r) * (H_DIM * 2) + ((sslot ^ (r & 7)) << 4);
    }

    f32x4 acc[4][4];
    const f32x4 zero4 = {0.f, 0.f, 0.f, 0.f};
#pragma unroll
    for (int i = 0; i < 4; ++i)
#pragma unroll
        for (int j = 0; j < 4; ++j) acc[i][j] = zero4;

    for (int kt = 0; kt < H_DIM / BK; ++kt) {
        __syncthreads();
#pragma unroll
        for (int p = 0; p < 4; ++p) {
            load16_to_lds(agp[p] + kt * (BK * 2), albuf + w * 4096 + p * 1024);
            load16_to_lds(bgp[p] + kt * (BK * 2), blbuf + w * 4096 + p * 1024);
        }
        __syncthreads();   // drains vmcnt + lgkm before compute

#pragma unroll
        for (int kk = 0; kk < 2; ++kk) {
            short8 af[4], bfr[4];
#pragma unroll
            for (int f = 0; f < 4; ++f) {
                const int ra = wm * 64 + f * 16 + (lane & 15);
                const int sa = (kk * 4 + (lane >> 4)) ^ (ra & 7);
                af[f] = *(const short8*)(albuf + ra * 128 + sa * 16);
                const int rb = wn * 64 + f * 16 + (lane & 15);
                const int sb = (kk * 4 + (lane >> 4)) ^ (rb & 7);
                bfr[f] = *(const short8*)(blbuf + rb * 128 + sb * 16);
            }
#pragma unroll
            for (int i = 0; i < 4; ++i)
#pragma unroll
                for (int j = 0; j < 4; ++j)
                    acc[i][j] = __builtin_amdgcn_mfma_f32_16x16x32_bf16(af[i], bfr[j], acc[i][j], 0, 0, 0);
        }
    }

    // Epilogue: C/D map row = 4*(lane>>4)+q, col = lane&15 (per frag).
    // Thread's rows: (fi,q); cols: fj*16 + (lane&15). Top-2 per row, then
    // 16-lane shfl reduce, write per (block, wn) chunk partial.
    const int g = lane >> 4;
    const int cl = lane & 15;
    const int pc = nt * 2 + wn;
#pragma unroll
    for (int fi = 0; fi < 4; ++fi) {
#pragma unroll
        for (int q = 0; q < 4; ++q) {
            float v1 = -FLT_MAX, v2 = -FLT_MAX;
            int   i1 = 0x7fffffff, i2 = 0x7fffffff;
#pragma unroll
            for (int fj = 0; fj < 4; ++fj) {
                const int cin = wn * 64 + fj * 16 + cl;
                const int col = n0 + cin;
                float v = acc[fi][fj][q] + bl[cin];
                if (col >= NVP1) v = -FLT_MAX;
                if (v > v1 || (v == v1 && col < i1)) { v2 = v1; i2 = i1; v1 = v; i1 = col; }
                else if (v > v2 || (v == v2 && col < i2)) { v2 = v; i2 = col; }
            }
#pragma unroll
            for (int m = 1; m < 16; m <<= 1) {
                const float ov1 = __shfl_xor(v1, m, 64);
                const int   oi1 = __shfl_xor(i1, m, 64);
                const float ov2 = __shfl_xor(v2, m, 64);
                const int   oi2 = __shfl_xor(i2, m, 64);
                if (ov1 > v1 || (ov1 == v1 && oi1 < i1)) {
                    float nv2; int ni2;
                    if (v1 > ov2 || (v1 == ov2 && i1 < oi2)) { nv2 = v1; ni2 = i1; }
                    else                                     { nv2 = ov2; ni2 = oi2; }
                    v1 = ov1; i1 = oi1; v2 = nv2; i2 = ni2;
                } else {
                    if (ov1 > v2 || (ov1 == v2 && oi1 < i2)) { v2 = ov1; i2 = oi1; }
                }
            }
            if (cl == 0) {
                const int row = m0 + wm * 64 + fi * 16 + g * 4 + q;
                pv1[(size_t)pc * M_TOT + row] = v1;
                pi1[(size_t)pc * M_TOT + row] = i1;
                pv2[(size_t)pc * M_TOT + row] = v2;
                pi2[(size_t)pc * M_TOT + row] = i2;
            }
        }
    }
}

// ---------------------------------------------------------------------------
// Merge 80 chunk-partials per token; flag ambiguous tokens for fp32 rescore.
// ---------------------------------------------------------------------------
__device__ __forceinline__ void ins8(float v, int id, float tv[8], int ti[8]) {
#pragma unroll
    for (int s = 0; s < 8; ++s) {
        const bool b = (v > tv[s]) || (v == tv[s] && id < ti[s]);
        const float nv = b ? v : tv[s]; const int ni = b ? id : ti[s];
        v = b ? tv[s] : v; id = b ? ti[s] : id;
        tv[s] = nv; ti[s] = ni;
    }
}

__global__ __launch_bounds__(256)
void merge_kernel(const float* __restrict__ pv1, const int* __restrict__ pi1,
                  const float* __restrict__ pv2, const int* __restrict__ pi2,
                  int* __restrict__ fidx, int* __restrict__ counter, int* __restrict__ jobs)
{
    const int token = blockIdx.x * 256 + threadIdx.x;
    float tv[8]; int ti[8];
#pragma unroll
    for (int s = 0; s < 8; ++s) { tv[s] = -FLT_MAX; ti[s] = 0x7fffffff; }
    for (int pc = 0; pc < NCHUNK; ++pc) {
        ins8(pv1[(size_t)pc * M_TOT + token], pi1[(size_t)pc * M_TOT + token], tv, ti);
        ins8(pv2[(size_t)pc * M_TOT + token], pi2[(size_t)pc * M_TOT + token], tv, ti);
    }
    int cnt = 0;
#pragma unroll
    for (int s = 0; s < 8; ++s)
        if (ti[s] != 0x7fffffff && tv[s] >= tv[0] - MARGIN) cnt++;
    fidx[token] = ti[0];
    if (cnt > 1) {
        const int slot = atomicAdd(counter, 1);
        int* jp = jobs + (size_t)slot * 12;
        jp[0] = token;
        jp[1] = cnt;
#pragma unroll
        for (int s = 0; s < 8; ++s) jp[2 + s] = ti[s];
    }
}

// ---------------------------------------------------------------------------
// Exact fp32 rescore of candidate sets (<=8 dots per flagged token).
// ---------------------------------------------------------------------------
__global__ __launch_bounds__(256)
void rescore_kernel(const float* __restrict__ x, const float* __restrict__ gw,
                    const float* __restrict__ gb, const int* __restrict__ jobs,
                    const int* __restrict__ counter, int* __restrict__ fidx)
{
    __shared__ float sv[8];
    __shared__ int   si[8];
    __shared__ int   sjob[10];
    const int njobs = counter[0];
    const int t = threadIdx.x;
    for (int j = blockIdx.x; j < njobs; j += gridDim.x) {
        if (t < 10) sjob[t] = jobs[(size_t)j * 12 + t];
        __syncthreads();
        const int token = sjob[0];
        const int g  = t >> 5;
        const int sl = t & 31;
        const int cand = sjob[2 + g];
        float v = -FLT_MAX;
        if (cand <= NV) {
            const float4* xr = (const float4*)(x + (size_t)token * H_DIM);
            const float4* wr = (const float4*)(gw + (size_t)cand * H_DIM);
            float s = 0.f;
            for (int k = sl; k < H_DIM / 4; k += 32) {
                const float4 a = xr[k], b = wr[k];
                s = fmaf(a.x, b.x, s); s = fmaf(a.y, b.y, s);
                s = fmaf(a.z, b.z, s); s = fmaf(a.w, b.w, s);
            }
#pragma unroll
            for (int m = 1; m < 32; m <<= 1) s += __shfl_xor(s, m, 64);
            v = s + gb[cand];
        }
        if (sl == 0) { sv[g] = v; si[g] = (cand <= NV) ? cand : 0x7fffffff; }
        __syncthreads();
        if (t == 0) {
            float bv = sv[0]; int bi = si[0];
#pragma unroll
            for (int q = 1; q < 8; ++q)
                if (sv[q] > bv || (sv[q] == bv && si[q] < bi)) { bv = sv[q]; bi = si[q]; }
            fidx[token] = bi;
        }
        __syncthreads();
    }
}

// ---------------------------------------------------------------------------
// Final gather
// ---------------------------------------------------------------------------
__global__ __launch_bounds__(256)
void gather_kernel(const float* __restrict__ x, const float* __restrict__ pool,
                   const int* __restrict__ fidx, float* __restrict__ out)
{
    const int token = blockIdx.x;
    const int idx = fidx[token];
    const float4* src;
    if (idx == NV) {
        src = (const float4*)(x + (size_t)token * H_DIM);
    } else {
        const int safe = (idx < NV) ? idx : (NV - 1);
        src = (const float4*)(pool + (size_t)safe * POOL_ROW_STRIDE + POOL_LAYER_OFF);
    }
    float4* dst = (float4*)(out + (size_t)token * H_DIM);
    dst[threadIdx.x]       = src[threadIdx.x];
    dst[threadIdx.x + 256] = src[threadIdx.x + 256];
}

extern "C" void kernel_launch(void* const* d_in, const int* in_sizes, int n_in,
                              void* d_out, int out_size, void* d_ws, size_t ws_size,
                              hipStream_t stream)
{
    const float* x    = (const float*)d_in[0];
    const float* gw   = (const float*)d_in[1];
    const float* gb   = (const float*)d_in[2];
    const float* pool = (const float*)d_in[3];
    float* out = (float*)d_out;

    // x_bf parked in d_out (67 MB of 134 MB; gather fully overwrites d_out later)
    unsigned short* xbf = (unsigned short*)d_out;

    // ws layout
    char* wsb = (char*)d_ws;
    unsigned short* wbf = (unsigned short*)wsb;                       // 5120*2048*2 = 20.97 MB
    size_t off = (size_t)N_PAD * H_DIM * 2;
    float* pv1 = (float*)(wsb + off); off += (size_t)NCHUNK * M_TOT * 4;
    int*   pi1 = (int*)  (wsb + off); off += (size_t)NCHUNK * M_TOT * 4;
    float* pv2 = (float*)(wsb + off); off += (size_t)NCHUNK * M_TOT * 4;
    int*   pi2 = (int*)  (wsb + off); off += (size_t)NCHUNK * M_TOT * 4;
    int*   fidx = (int*)(wsb + off);  off += (size_t)M_TOT * 4;
    int*   counter = (int*)(wsb + off); off += 256;
    int*   jobs = (int*)(wsb + off);  // MAXJOBS * 12 ints = 768 KB

    hipMemsetAsync(counter, 0, sizeof(int), stream);

    conv_x_kernel<<<4096, 256, 0, stream>>>(x, xbf);
    conv_w_kernel<<<2560, 256, 0, stream>>>(gw, wbf);

    gemm_top2_kernel<<<(M_TOT / BM) * NTILES, 256, 0, stream>>>(xbf, wbf, gb, pv1, pi1, pv2, pi2);

    merge_kernel<<<M_TOT / 256, 256, 0, stream>>>(pv1, pi1, pv2, pi2, fidx, counter, jobs);
    rescore_kernel<<<256, 256, 0, stream>>>(x, gw, gb, jobs, counter, fidx);
    gather_kernel<<<M_TOT, 256, 0, stream>>>(x, pool, fidx, out);
}